// Round 7
// baseline (1909.920 us; speedup 1.0000x reference)
//
#include <hip/hip_runtime.h>
#include <hip/hip_bf16.h>
#include <math.h>

#define GENES 1000
#define LATENT 128
#define HID 512
#define NB 128   // batch

typedef short bf16x8 __attribute__((ext_vector_type(8)));
typedef float f32x4 __attribute__((ext_vector_type(4)));

// fp32 -> bf16 RNE via hardware cvt (compiler fuses pairs into v_cvt_pk_bf16_f32)
static __device__ __forceinline__ ushort f2bf(float f) {
    __hip_bfloat16 h = __float2bfloat16(f);
    return __builtin_bit_cast(ushort, h);
}

static __device__ __forceinline__ float gelu_exact(float x) {
    return 0.5f * x * (1.0f + erff(x * 0.70710678118654752440f));
}

// One workgroup per gene; 512 threads = 8 waves. Sequential layers:
//   stage x (bf16, LDS, aliased into h1s) -> L1 (acc1 regs) -> GELU -> h1 [128x512] bf16 LDS
//   -> L2 K=512 (acc2 regs) -> GELU -> dot W3 (regs+shfl) -> cross-wave reduce in
//   reused h1s bytes -> out.
// acc1/acc2 never co-live => peak ~210 VGPR, no spill at the 2-waves/EU 256 cap.
// Total LDS = exactly 131072 B. Memory-bound: 1.32 GB weights read exactly once.
__global__ __launch_bounds__(512, 2) void genewise_kernel(
    const float* __restrict__ x,
    const float* __restrict__ W1,
    const float* __restrict__ b1,
    const float* __restrict__ W2,
    const float* __restrict__ b2,
    const float* __restrict__ W3,
    const float* __restrict__ b3,
    float* __restrict__ out)
{
    const int g   = blockIdx.x;
    const int tid = threadIdx.x;
    const int w   = tid >> 6;     // wave id 0..7
    const int l   = tid & 63;     // lane
    const int l15 = l & 15;
    const int lq  = l >> 4;       // 0..3

    // h1s: full h1 [n=128][e=512] bf16, XOR-swizzled (131072 B).
    // First 32 KB doubles as the x staging buffer [n=128][k=128] bf16 (x fully
    // consumed by L1 before h1 overwrites it; barrier between). First 512 B
    // re-reused again after L2 as the fp32 cross-wave output accumulator.
    __shared__ __align__(16) ushort h1s[NB * HID];

    // ---- stage x -> LDS bf16, swizzle: u16 index ^ ((row&7)<<3) ----
    #pragma unroll
    for (int i = 0; i < 8; ++i) {
        int idx = (i * 512 + tid) * 4;       // 4 consecutive fp32
        int row = idx >> 7;                  // / LATENT
        int col = idx & (LATENT - 1);
        const float4 v = *reinterpret_cast<const float4*>(&x[idx]);
        ushort4 bb;
        bb.x = f2bf(v.x); bb.y = f2bf(v.y); bb.z = f2bf(v.z); bb.w = f2bf(v.w);
        int u16i = (row * LATENT + col) ^ ((row & 7) << 3);
        *reinterpret_cast<ushort4*>(&h1s[u16i]) = bb;
    }
    __syncthreads();

    const int eb = w * 64;                   // this wave's 64-col slice (layers 1..3)

    // ===== layer 1: acc1[mt][nt] = x @ W1, e = eb + nt*16 + l15 =====
    f32x4 acc1[8][4];
    #pragma unroll
    for (int mt = 0; mt < 8; ++mt)
        #pragma unroll
        for (int nt = 0; nt < 4; ++nt)
            acc1[mt][nt] = f32x4{0.f, 0.f, 0.f, 0.f};

    #pragma unroll 1
    for (int kt = 0; kt < 4; ++kt) {         // K = 128, 32/step
        const int k1 = kt * 32 + lq * 8;
        // batch all global weight loads first (32 dwords/lane)
        float wv[4][8];
        #pragma unroll
        for (int nt = 0; nt < 4; ++nt) {
            const int e = eb + nt * 16 + l15;
            const float* p = W1 + ((size_t)g * LATENT + k1) * HID + e;
            #pragma unroll
            for (int j = 0; j < 8; ++j) wv[nt][j] = p[(size_t)j * HID];
        }
        // A fragments from LDS (x region)
        bf16x8 af[8];
        #pragma unroll
        for (int mt = 0; mt < 8; ++mt) {
            const int row  = mt * 16 + l15;
            const int u16i = (row * LATENT + k1) ^ ((row & 7) << 3);
            af[mt] = *reinterpret_cast<const bf16x8*>(&h1s[u16i]);
        }
        // convert + MFMA
        #pragma unroll
        for (int nt = 0; nt < 4; ++nt) {
            bf16x8 bfr;
            #pragma unroll
            for (int j = 0; j < 8; ++j) bfr[j] = (short)f2bf(wv[nt][j]);
            #pragma unroll
            for (int mt = 0; mt < 8; ++mt)
                acc1[mt][nt] = __builtin_amdgcn_mfma_f32_16x16x32_bf16(af[mt], bfr, acc1[mt][nt], 0, 0, 0);
        }
    }
    __syncthreads();   // all waves done reading x region; safe to overwrite with h1

    // ---- epilogue 1: bias + exact GELU -> h1s [n*HID + e] swizzled ----
    #pragma unroll
    for (int nt = 0; nt < 4; ++nt) {
        const int e    = eb + nt * 16 + l15;
        const float bias = b1[(size_t)g * HID + e];
        #pragma unroll
        for (int mt = 0; mt < 8; ++mt) {
            #pragma unroll
            for (int r = 0; r < 4; ++r) {
                const int n  = mt * 16 + lq * 4 + r;
                const float hv = gelu_exact(acc1[mt][nt][r] + bias);
                h1s[(n * HID + e) ^ ((n & 7) << 3)] = f2bf(hv);
            }
        }
    }
    __syncthreads();

    // ===== layer 2: acc2[mt][nt] = h1 @ W2, K = 512, d2 = eb + nt*16 + l15 =====
    f32x4 acc2[8][4];
    #pragma unroll
    for (int mt = 0; mt < 8; ++mt)
        #pragma unroll
        for (int nt = 0; nt < 4; ++nt)
            acc2[mt][nt] = f32x4{0.f, 0.f, 0.f, 0.f};

    #pragma unroll 1
    for (int kt = 0; kt < 16; ++kt) {        // K = 512, 32/step
        const int kg = kt * 32 + lq * 8;
        float wv[4][8];
        #pragma unroll
        for (int nt = 0; nt < 4; ++nt) {
            const int d2 = eb + nt * 16 + l15;
            const float* p = W2 + ((size_t)g * HID + kg) * HID + d2;
            #pragma unroll
            for (int j = 0; j < 8; ++j) wv[nt][j] = p[(size_t)j * HID];
        }
        bf16x8 af[8];
        #pragma unroll
        for (int mt = 0; mt < 8; ++mt) {
            const int row  = mt * 16 + l15;
            const int u16i = (row * HID + kg) ^ ((row & 7) << 3);
            af[mt] = *reinterpret_cast<const bf16x8*>(&h1s[u16i]);
        }
        #pragma unroll
        for (int nt = 0; nt < 4; ++nt) {
            bf16x8 bfr;
            #pragma unroll
            for (int j = 0; j < 8; ++j) bfr[j] = (short)f2bf(wv[nt][j]);
            #pragma unroll
            for (int mt = 0; mt < 8; ++mt)
                acc2[mt][nt] = __builtin_amdgcn_mfma_f32_16x16x32_bf16(af[mt], bfr, acc2[mt][nt], 0, 0, 0);
        }
    }

    // ===== layer 3: out[n] = sum_d2 gelu(h2[n][d2] + b2) * W3[d2] + b3, fp32 =====
    // h1s is dead now; reuse its first 512 B as the fp32 cross-wave accumulator.
    __syncthreads();                          // all waves finished reading h1s
    float* red = reinterpret_cast<float*>(h1s);
    if (tid < NB) red[tid] = 0.0f;
    __syncthreads();

    float b2v[4], w3v[4];
    #pragma unroll
    for (int nt = 0; nt < 4; ++nt) {
        const int d2 = eb + nt * 16 + l15;
        b2v[nt] = b2[(size_t)g * HID + d2];
        w3v[nt] = W3[(size_t)g * HID + d2];
    }
    #pragma unroll
    for (int mt = 0; mt < 8; ++mt) {
        #pragma unroll
        for (int r = 0; r < 4; ++r) {
            float s = 0.f;
            #pragma unroll
            for (int nt = 0; nt < 4; ++nt)
                s += gelu_exact(acc2[mt][nt][r] + b2v[nt]) * w3v[nt];
            // reduce over the 16 lanes (l&15) holding different d2
            s += __shfl_xor(s, 1, 64);
            s += __shfl_xor(s, 2, 64);
            s += __shfl_xor(s, 4, 64);
            s += __shfl_xor(s, 8, 64);
            if (l15 == 0) atomicAdd(&red[mt * 16 + lq * 4 + r], s);
        }
    }
    __syncthreads();
    if (tid < NB) out[(size_t)tid * GENES + g] = red[tid] + b3[g];
}

extern "C" void kernel_launch(void* const* d_in, const int* in_sizes, int n_in,
                              void* d_out, int out_size, void* d_ws, size_t ws_size,
                              hipStream_t stream) {
    const float* x  = (const float*)d_in[0];
    const float* W1 = (const float*)d_in[1];
    const float* b1 = (const float*)d_in[2];
    const float* W2 = (const float*)d_in[3];
    const float* b2 = (const float*)d_in[4];
    const float* W3 = (const float*)d_in[5];
    const float* b3 = (const float*)d_in[6];
    float* out = (float*)d_out;
    hipLaunchKernelGGL(genewise_kernel, dim3(GENES), dim3(512), 0, stream,
                       x, W1, b1, W2, b2, W3, b3, out);
}